// Round 5
// baseline (386.021 us; speedup 1.0000x reference)
//
#include <hip/hip_runtime.h>

// FlashAttentionBlock: B=2, S=4096, D=1024, TILE=128 (per-tile softmax)
// R5: all four GEMMs on the proven gemm128 pipeline (BM=128, BN=256, BK=64,
// 2 phases/K-tile, 3-deep LDS ring, vmcnt(6) steady state, setprio, XOR
// slot swizzle). Scores softmax fused into the epilogue (EPI=3) with a
// cross-wave-pair LDS reduction. R4's 2-buffer 256^2 schedule removed (its
// vmcnt wait had only 1-phase latency cover -> HBM-latency stall).

#define D_ 1024
#define S_ 4096
#define B_ 2

typedef unsigned short u16;
typedef float f32x4 __attribute__((ext_vector_type(4)));
typedef float float4v __attribute__((ext_vector_type(4)));
typedef __bf16 bf16x8 __attribute__((ext_vector_type(8)));
typedef unsigned short us8 __attribute__((ext_vector_type(8)));

static __device__ __forceinline__ u16 f2bf(float f) {
    unsigned int u = __builtin_bit_cast(unsigned int, f);
    u += 0x7FFFu + ((u >> 16) & 1u);   // RNE
    return (u16)(u >> 16);
}

static __device__ __forceinline__ void gld16(const u16* g, u16* l) {
    __builtin_amdgcn_global_load_lds(
        (const __attribute__((address_space(1))) void*)g,
        (__attribute__((address_space(3))) void*)l, 16, 0, 0);
}

template <int N>
static __device__ __forceinline__ void waitv() {
    if constexpr (N == 0)      asm volatile("s_waitcnt vmcnt(0)" ::: "memory");
    else if constexpr (N == 6) asm volatile("s_waitcnt vmcnt(6)" ::: "memory");
}

static __device__ __forceinline__ void lgkm0sb() {
    asm volatile("s_waitcnt lgkmcnt(0)" ::: "memory");
    __builtin_amdgcn_sched_barrier(0);
}

// XCD-chunked swizzle (requires gridDim.y % 8 == 0; bijective).
static __device__ __forceinline__ void xcd_map(int& bx, int& by) {
    const int gx = gridDim.x, gy = gridDim.y;
    int lin = blockIdx.x + blockIdx.y * gx;
    int ry = gy >> 3;
    int idx = lin >> 3;
    int q = idx / ry;
    bx = q;
    by = (lin & 7) * ry + (idx - q * ry);
}

// ---------------- cast kernels ----------------
__global__ void cast_kernel(const float* __restrict__ in, u16* __restrict__ out, int n8) {
    int i = blockIdx.x * blockDim.x + threadIdx.x;
    int stride = gridDim.x * blockDim.x;
    for (; i < n8; i += stride) {
        const float4v* p = (const float4v*)in + 2 * (size_t)i;
        float4v a = p[0], b = p[1];
        us8 o;
        o[0] = f2bf(a[0]); o[1] = f2bf(a[1]); o[2] = f2bf(a[2]); o[3] = f2bf(a[3]);
        o[4] = f2bf(b[0]); o[5] = f2bf(b[1]); o[6] = f2bf(b[2]); o[7] = f2bf(b[3]);
        *((us8*)out + i) = o;
    }
}

__global__ void cast4_kernel(const float* __restrict__ w0, const float* __restrict__ w1,
                             const float* __restrict__ w2, const float* __restrict__ w3,
                             u16* __restrict__ out, int n8per) {
    const float* srcs[4] = {w0, w1, w2, w3};
    const float* in = srcs[blockIdx.y];
    u16* o = out + (size_t)blockIdx.y * (size_t)n8per * 8;
    int i = blockIdx.x * blockDim.x + threadIdx.x;
    int stride = gridDim.x * blockDim.x;
    for (; i < n8per; i += stride) {
        const float4v* p = (const float4v*)in + 2 * (size_t)i;
        float4v a = p[0], b = p[1];
        us8 v;
        v[0] = f2bf(a[0]); v[1] = f2bf(a[1]); v[2] = f2bf(a[2]); v[3] = f2bf(a[3]);
        v[4] = f2bf(b[0]); v[5] = f2bf(b[1]); v[6] = f2bf(b[2]); v[7] = f2bf(b[3]);
        *((us8*)o + i) = v;
    }
}

__global__ void concat_bias(const float* __restrict__ b0, const float* __restrict__ b1,
                            const float* __restrict__ b2, float* __restrict__ out) {
    int i = blockIdx.x * 256 + threadIdx.x;   // 3072 threads
    const float* s = (i < 1024) ? b0 : ((i < 2048) ? b1 : b2);
    out[i] = s[i & 1023];
}

// ---------------- bf16 transpose (V -> V^T per batch), V row stride ldv ----
__global__ void transpose_v(const u16* __restrict__ V, u16* __restrict__ Vt, int ldv) {
    __shared__ u16 t[64][72];
    const int tid = threadIdx.x;
    const int d0 = blockIdx.x * 64;
    const int s0 = blockIdx.y * 64;
    const u16* Vb = V + (size_t)blockIdx.z * ((size_t)S_ * ldv);
    u16* Vtb = Vt + (size_t)blockIdx.z * ((size_t)D_ * S_);
#pragma unroll
    for (int it = 0; it < 2; it++) {
        int idx = it * 256 + tid;
        int row = idx >> 3;
        int ch = idx & 7;
        us8 v = *(const us8*)&Vb[(size_t)(s0 + row) * ldv + d0 + ch * 8];
        *(us8*)&t[row][ch * 8] = v;
    }
    __syncthreads();
#pragma unroll
    for (int it = 0; it < 2; it++) {
        int idx = it * 256 + tid;
        int jj = idx >> 3;
        int ch = idx & 7;
        us8 v;
#pragma unroll
        for (int e = 0; e < 8; e++) v[e] = t[ch * 8 + e][jj];
        *(us8*)&Vtb[(size_t)(d0 + jj) * S_ + s0 + ch * 8] = v;
    }
}

#define MMQ(ACC, MB, NB)                                                      \
    {                                                                         \
        _Pragma("unroll") for (int mi_ = 0; mi_ < 4; ++mi_) {                 \
            _Pragma("unroll") for (int ni_ = 0; ni_ < 2; ++ni_) {             \
                _Pragma("unroll") for (int kh_ = 0; kh_ < 2; ++kh_) {         \
                    ACC[(MB) + mi_][(NB) + ni_] =                             \
                        __builtin_amdgcn_mfma_f32_16x16x32_bf16(              \
                            af[mi_][kh_], bf[ni_][kh_],                       \
                            ACC[(MB) + mi_][(NB) + ni_], 0, 0, 0);            \
                }                                                             \
            }                                                                 \
        }                                                                     \
    }

// ---------------- gemm128: 128x256, 2 phases/K-tile, 3-deep ring -----------
// EPI 0: bf16 out + f32 bias; 1: bf16 out * scale; 2: f32 out + bias;
// 3: per-128-col-tile softmax (scores), bf16 out.
template <int EPI>
__global__ __launch_bounds__(512, 1) void gemm128(
    const u16* __restrict__ A, const u16* __restrict__ B, void* __restrict__ Cv,
    const float* __restrict__ bias, int K, int lda, int ldb, int ldc,
    long sA, long sB, long sC, float scale)
{
    __shared__ u16 lA[3][128 * 64];
    __shared__ u16 lB[3][256 * 64];
    __shared__ float sred[2][8][64];   // EPI==3 only
    const int tid = threadIdx.x, lane = tid & 63, wid = tid >> 6;
    const int wr = wid >> 2, wc = wid & 3;
    const int ar = lane & 15, sl = lane >> 4;
    const int z = blockIdx.z;
    A += (size_t)z * sA;
    B += (size_t)z * sB;
    int bx, by;
    xcd_map(bx, by);
    const int m0 = by * 128, n0 = bx * 256;
    const int NT = K >> 6;

    f32x4 acc[4][4];
#pragma unroll
    for (int i = 0; i < 4; i++)
#pragma unroll
        for (int j = 0; j < 4; j++)
#pragma unroll
            for (int r = 0; r < 4; r++) acc[i][j][r] = 0.0f;

    auto stgA = [&](int t) {
        u16* dst = &lA[t % 3][0];
#pragma unroll
        for (int j = 0; j < 2; ++j) {
            const int u = j * 512 + wid * 64 + lane;
            const int row = u >> 3;
            const int ls = (u & 7) ^ (row & 7);
            gld16(A + (size_t)(m0 + row) * lda + (t << 6) + ls * 8, dst + u * 8);
        }
    };
    auto stgB = [&](int t, int h) {
        u16* dst = &lB[t % 3][0];
#pragma unroll
        for (int j = 0; j < 2; ++j) {
            const int u = j * 512 + wid * 64 + lane;
            const int row = h * 128 + (u >> 3);
            const int ls = (u & 7) ^ (row & 7);
            gld16(B + (size_t)(n0 + row) * ldb + (t << 6) + ls * 8, dst + h * 8192 + u * 8);
        }
    };
    auto rd = [&](const u16* l, int R, int kh) -> bf16x8 {
        const int ps = ((kh << 2) | sl) ^ (R & 7);
        return *(const bf16x8*)&l[R * 64 + ps * 8];
    };

    // prologue: tiles 0 and 1 fully staged (12 loads)
    stgA(0); stgB(0, 0); stgB(0, 1);
    stgA(1); stgB(1, 0); stgB(1, 1);
    waitv<6>();
    __builtin_amdgcn_s_barrier();

    bf16x8 af[4][2], bf[2][2];
    for (int t = 0; t < NT; ++t) {
        const u16* bufA = &lA[t % 3][0];
        const u16* bufB = &lB[t % 3][0];
        const bool s2 = (t + 2 < NT);
        // ---- P1: A(all mi) + B(ni0-1); stage A(t+2), B-lo(t+2)
#pragma unroll
        for (int mi = 0; mi < 4; ++mi)
#pragma unroll
            for (int kh = 0; kh < 2; ++kh)
                af[mi][kh] = rd(bufA, wr * 64 + mi * 16 + ar, kh);
#pragma unroll
        for (int ni = 0; ni < 2; ++ni)
#pragma unroll
            for (int kh = 0; kh < 2; ++kh)
                bf[ni][kh] = rd(bufB, wc * 64 + ni * 16 + ar, kh);
        if (s2) { stgA(t + 2); stgB(t + 2, 0); }
        lgkm0sb();
        __builtin_amdgcn_s_setprio(1);
        MMQ(acc, 0, 0);
        __builtin_amdgcn_s_setprio(0);
        __builtin_amdgcn_s_barrier();
        // ---- P2: B(ni2-3); stage B-hi(t+2); vmcnt covers tile t+1
#pragma unroll
        for (int ni = 0; ni < 2; ++ni)
#pragma unroll
            for (int kh = 0; kh < 2; ++kh)
                bf[ni][kh] = rd(bufB, wc * 64 + (2 + ni) * 16 + ar, kh);
        if (s2) stgB(t + 2, 1);
        lgkm0sb();
        __builtin_amdgcn_s_setprio(1);
        MMQ(acc, 0, 2);
        __builtin_amdgcn_s_setprio(0);
        if (s2) waitv<6>(); else waitv<0>();
        __builtin_amdgcn_s_barrier();
    }

    // ---------------- epilogue ----------------
    if constexpr (EPI == 3) {
        // per-128-col-tile softmax: col group = wave pair (wid^1), rows = 64/wave
        const float SL = 0.03125f * 1.44269504088896341f;  // 1/sqrt(D)*log2(e)
#pragma unroll
        for (int mi = 0; mi < 4; mi++) {
#pragma unroll
            for (int r = 0; r < 4; r++) {
                float m = acc[mi][0][r];
#pragma unroll
                for (int ni = 1; ni < 4; ni++) m = fmaxf(m, acc[mi][ni][r]);
                m = fmaxf(m, __shfl_xor(m, 1));
                m = fmaxf(m, __shfl_xor(m, 2));
                m = fmaxf(m, __shfl_xor(m, 4));
                m = fmaxf(m, __shfl_xor(m, 8));
                if (ar == 0) sred[0][wid][mi * 16 + sl * 4 + r] = m;
            }
        }
        __syncthreads();
#pragma unroll
        for (int mi = 0; mi < 4; mi++) {
#pragma unroll
            for (int r = 0; r < 4; r++) {
                const int rl = mi * 16 + sl * 4 + r;
                const float mc = fmaxf(sred[0][wid][rl], sred[0][wid ^ 1][rl]);
                float s = 0.0f;
#pragma unroll
                for (int ni = 0; ni < 4; ni++) {
                    float e = exp2f((acc[mi][ni][r] - mc) * SL);
                    acc[mi][ni][r] = e;
                    s += e;
                }
                s += __shfl_xor(s, 1);
                s += __shfl_xor(s, 2);
                s += __shfl_xor(s, 4);
                s += __shfl_xor(s, 8);
                if (ar == 0) sred[1][wid][rl] = s;
            }
        }
        __syncthreads();
        u16* C = (u16*)Cv + (size_t)z * sC;
#pragma unroll
        for (int mi = 0; mi < 4; mi++) {
#pragma unroll
            for (int r = 0; r < 4; r++) {
                const int rl = mi * 16 + sl * 4 + r;
                const float inv = 1.0f / (sred[1][wid][rl] + sred[1][wid ^ 1][rl]);
                const int row = m0 + wr * 64 + rl;
#pragma unroll
                for (int ni = 0; ni < 4; ni++)
                    C[(size_t)row * ldc + n0 + wc * 64 + ni * 16 + ar] =
                        f2bf(acc[mi][ni][r] * inv);
            }
        }
    } else {
#pragma unroll
        for (int mi = 0; mi < 4; mi++) {
#pragma unroll
            for (int ni = 0; ni < 4; ni++) {
                const int col = n0 + wc * 64 + ni * 16 + ar;
                const int rowb = m0 + wr * 64 + mi * 16 + sl * 4;
                if constexpr (EPI == 0) {
                    u16* C = (u16*)Cv + (size_t)z * sC;
                    const float bv = bias[col];
#pragma unroll
                    for (int r = 0; r < 4; r++)
                        C[(size_t)(rowb + r) * ldc + col] = f2bf(acc[mi][ni][r] + bv);
                } else if constexpr (EPI == 1) {
                    u16* C = (u16*)Cv + (size_t)z * sC;
#pragma unroll
                    for (int r = 0; r < 4; r++)
                        C[(size_t)(rowb + r) * ldc + col] = f2bf(acc[mi][ni][r] * scale);
                } else {
                    float* C = (float*)Cv + (size_t)z * sC;
                    const float bv = bias[col];
#pragma unroll
                    for (int r = 0; r < 4; r++)
                        C[(size_t)(rowb + r) * ldc + col] = acc[mi][ni][r] + bv;
                }
            }
        }
    }
}

// ---------------- launch ----------------
extern "C" void kernel_launch(void* const* d_in, const int* in_sizes, int n_in,
                              void* d_out, int out_size, void* d_ws, size_t ws_size,
                              hipStream_t stream)
{
    const float* X  = (const float*)d_in[0];
    const float* Wq = (const float*)d_in[1];
    const float* bq = (const float*)d_in[2];
    const float* Wk = (const float*)d_in[3];
    const float* bk = (const float*)d_in[4];
    const float* Wv = (const float*)d_in[5];
    const float* bv = (const float*)d_in[6];
    const float* Wo = (const float*)d_in[7];
    const float* bo = (const float*)d_in[8];
    float* OUT = (float*)d_out;

    u16* ws = (u16*)d_ws;
    const size_t NTOK = (size_t)B_ * S_;         // 8192
    const size_t XSZ = NTOK * D_;                // 8.39M elems
    u16* Xb   = ws;                              // [8192,1024] (reused as Ob)
    u16* QKVb = Xb + XSZ;                        // [8192,3072]
    u16* Vt   = QKVb + NTOK * (size_t)(3 * D_);  // [B][1024][4096]
    u16* Wqb  = Vt + XSZ;                        // [Wq;Wk;Wv;Wo] contiguous
    u16* Wsm  = Wqb + (size_t)4 * D_ * D_;       // [B][4096][4096]
    float* bqkv = (float*)(Wsm + (size_t)B_ * S_ * S_);  // [3072] f32
    u16* Ob   = Xb;

    u16* Qp = QKVb;
    u16* Kp = QKVb + D_;
    u16* Vp = QKVb + 2 * D_;
    const int ldqkv = 3 * D_;

    cast_kernel<<<dim3(2048), dim3(256), 0, stream>>>(X, Xb, (int)(XSZ / 8));
    cast4_kernel<<<dim3(512, 4), dim3(256), 0, stream>>>(Wq, Wk, Wv, Wo, Wqb,
                                                         (int)((size_t)D_ * D_ / 8));
    concat_bias<<<dim3(12), dim3(256), 0, stream>>>(bq, bk, bv, bqkv);

    // Fused QKV projection: [8192,1024] x [3072,1024]^T -> [8192,3072]
    gemm128<0><<<dim3(3 * D_ / 256, NTOK / 128, 1), 512, 0, stream>>>(
        Xb, Wqb, QKVb, bqkv, D_, D_, D_, ldqkv, 0, 0, 0, 1.0f);

    transpose_v<<<dim3(D_ / 64, S_ / 64, B_), 256, 0, stream>>>(Vp, Vt, ldqkv);

    // Scores + fused per-tile softmax: [4096,1024] x [4096,1024]^T
    gemm128<3><<<dim3(S_ / 256, S_ / 128, B_), 512, 0, stream>>>(
        Qp, Kp, Wsm, nullptr, D_, ldqkv, ldqkv, S_,
        (long)S_ * ldqkv, (long)S_ * ldqkv, (long)S_ * S_, 1.0f);

    // PV: [4096,4096] x [1024,4096]^T -> [4096,1024], scaled by 1/T
    gemm128<1><<<dim3(D_ / 256, S_ / 128, B_), 512, 0, stream>>>(
        Wsm, Vt, Ob, nullptr, S_, S_, S_, D_,
        (long)S_ * S_, (long)D_ * S_, (long)S_ * D_, 1.0f / (32.0f + 1e-6f));

    // Output projection: [8192,1024] x [1024,1024]^T -> f32 OUT
    gemm128<2><<<dim3(D_ / 256, NTOK / 128, 1), 512, 0, stream>>>(
        Ob, Wqb + (size_t)3 * D_ * D_, OUT, bo, D_, D_, D_, D_, 0, 0, 0, 1.0f);
}

// Round 8
// 370.653 us; speedup vs baseline: 1.0415x; 1.0415x over previous
//
#include <hip/hip_runtime.h>

// FlashAttentionBlock: B=2, S=4096, D=1024, TILE=128 (per-tile softmax)
// R6 (2nd resubmit after GPU acquisition timeouts): scores + fused-QKV on a
// faithful m201 8-phase 256x256 schedule:
//   BK=64, 2-deep double buffer, 1 half-tile (2 gld16/thread) staged/phase,
//   vmcnt(6) ONLY at phases 4 and 8 (3 half-tiles in flight, 4-phase
//   latency cover), B halves consumed in P1 / A halves by P2 so every
//   stage target is freed >=1 barrier before issue. 16 MFMA per phase.
// PV and out-proj stay on the gemm128 2-phase pipeline (grid-shape limits).

#define D_ 1024
#define S_ 4096
#define B_ 2

typedef unsigned short u16;
typedef float f32x4 __attribute__((ext_vector_type(4)));
typedef float float4v __attribute__((ext_vector_type(4)));
typedef __bf16 bf16x8 __attribute__((ext_vector_type(8)));
typedef unsigned short us8 __attribute__((ext_vector_type(8)));

static __device__ __forceinline__ u16 f2bf(float f) {
    unsigned int u = __builtin_bit_cast(unsigned int, f);
    u += 0x7FFFu + ((u >> 16) & 1u);   // RNE
    return (u16)(u >> 16);
}

static __device__ __forceinline__ void gld16(const u16* g, u16* l) {
    __builtin_amdgcn_global_load_lds(
        (const __attribute__((address_space(1))) void*)g,
        (__attribute__((address_space(3))) void*)l, 16, 0, 0);
}

template <int N>
static __device__ __forceinline__ void waitv() {
    if constexpr (N == 0)      asm volatile("s_waitcnt vmcnt(0)" ::: "memory");
    else if constexpr (N == 6) asm volatile("s_waitcnt vmcnt(6)" ::: "memory");
}

static __device__ __forceinline__ void lgkm0sb() {
    asm volatile("s_waitcnt lgkmcnt(0)" ::: "memory");
    __builtin_amdgcn_sched_barrier(0);
}

// XCD-chunked swizzle (bijective for gridDim.y % 8 == 0).
static __device__ __forceinline__ void xcd_map(int& bx, int& by) {
    const int gx = gridDim.x, gy = gridDim.y;
    int lin = blockIdx.x + blockIdx.y * gx;
    int ry = gy >> 3;
    int idx = lin >> 3;
    int q = idx / ry;
    bx = q;
    by = (lin & 7) * ry + (idx - q * ry);
}

// ---------------- cast kernels ----------------
__global__ void cast_kernel(const float* __restrict__ in, u16* __restrict__ out, int n8) {
    int i = blockIdx.x * blockDim.x + threadIdx.x;
    int stride = gridDim.x * blockDim.x;
    for (; i < n8; i += stride) {
        const float4v* p = (const float4v*)in + 2 * (size_t)i;
        float4v a = p[0], b = p[1];
        us8 o;
        o[0] = f2bf(a[0]); o[1] = f2bf(a[1]); o[2] = f2bf(a[2]); o[3] = f2bf(a[3]);
        o[4] = f2bf(b[0]); o[5] = f2bf(b[1]); o[6] = f2bf(b[2]); o[7] = f2bf(b[3]);
        *((us8*)out + i) = o;
    }
}

__global__ void cast4_kernel(const float* __restrict__ w0, const float* __restrict__ w1,
                             const float* __restrict__ w2, const float* __restrict__ w3,
                             u16* __restrict__ out, int n8per) {
    const float* srcs[4] = {w0, w1, w2, w3};
    const float* in = srcs[blockIdx.y];
    u16* o = out + (size_t)blockIdx.y * (size_t)n8per * 8;
    int i = blockIdx.x * blockDim.x + threadIdx.x;
    int stride = gridDim.x * blockDim.x;
    for (; i < n8per; i += stride) {
        const float4v* p = (const float4v*)in + 2 * (size_t)i;
        float4v a = p[0], b = p[1];
        us8 v;
        v[0] = f2bf(a[0]); v[1] = f2bf(a[1]); v[2] = f2bf(a[2]); v[3] = f2bf(a[3]);
        v[4] = f2bf(b[0]); v[5] = f2bf(b[1]); v[6] = f2bf(b[2]); v[7] = f2bf(b[3]);
        *((us8*)o + i) = v;
    }
}

__global__ void concat_bias(const float* __restrict__ b0, const float* __restrict__ b1,
                            const float* __restrict__ b2, float* __restrict__ out) {
    int i = blockIdx.x * 256 + threadIdx.x;   // 3072 threads
    const float* s = (i < 1024) ? b0 : ((i < 2048) ? b1 : b2);
    out[i] = s[i & 1023];
}

// ---------------- bf16 transpose (V -> V^T per batch), V row stride ldv ----
__global__ void transpose_v(const u16* __restrict__ V, u16* __restrict__ Vt, int ldv) {
    __shared__ u16 t[64][72];
    const int tid = threadIdx.x;
    const int d0 = blockIdx.x * 64;
    const int s0 = blockIdx.y * 64;
    const u16* Vb = V + (size_t)blockIdx.z * ((size_t)S_ * ldv);
    u16* Vtb = Vt + (size_t)blockIdx.z * ((size_t)D_ * S_);
#pragma unroll
    for (int it = 0; it < 2; it++) {
        int idx = it * 256 + tid;
        int row = idx >> 3;
        int ch = idx & 7;
        us8 v = *(const us8*)&Vb[(size_t)(s0 + row) * ldv + d0 + ch * 8];
        *(us8*)&t[row][ch * 8] = v;
    }
    __syncthreads();
#pragma unroll
    for (int it = 0; it < 2; it++) {
        int idx = it * 256 + tid;
        int jj = idx >> 3;
        int ch = idx & 7;
        us8 v;
#pragma unroll
        for (int e = 0; e < 8; e++) v[e] = t[ch * 8 + e][jj];
        *(us8*)&Vtb[(size_t)(d0 + jj) * S_ + s0 + ch * 8] = v;
    }
}

// 16-MFMA quadrant: mi in [MI0,MI0+4), ni in [NI0,NI0+2)
#define MM8(MI0, NI0)                                                         \
    {                                                                         \
        _Pragma("unroll") for (int mi_ = 0; mi_ < 4; ++mi_) {                 \
            _Pragma("unroll") for (int ni_ = 0; ni_ < 2; ++ni_) {             \
                _Pragma("unroll") for (int kh_ = 0; kh_ < 2; ++kh_) {         \
                    acc[(MI0) + mi_][(NI0) + ni_] =                           \
                        __builtin_amdgcn_mfma_f32_16x16x32_bf16(              \
                            af[(MI0) + mi_][kh_], bf[(NI0) + ni_][kh_],       \
                            acc[(MI0) + mi_][(NI0) + ni_], 0, 0, 0);          \
                }                                                             \
            }                                                                 \
        }                                                                     \
    }

// ---------------- gemm256: 256x256, m201 8-phase, 2-deep dbuf --------------
// EPI 0: bf16 out + f32 bias; 3: per-128-col-tile softmax, bf16 out.
template <int EPI>
__global__ __launch_bounds__(512, 1) void gemm256(
    const u16* __restrict__ A, const u16* __restrict__ B, void* __restrict__ Cv,
    const float* __restrict__ bias, int K, int lda, int ldb, int ldc,
    long sA, long sB, long sC)
{
    __shared__ u16 lA[2][256 * 64];
    __shared__ u16 lB[2][256 * 64];
    __shared__ float sred[2][8][128];
    const int tid = threadIdx.x, lane = tid & 63, wid = tid >> 6;
    const int wr = wid >> 2, wc = wid & 3;       // wave = (wr 0..1) x (wc 0..3)
    const int ar = lane & 15, sl = lane >> 4;
    const int z = blockIdx.z;
    A += (size_t)z * sA;
    B += (size_t)z * sB;
    int bx, by;
    xcd_map(bx, by);
    const int m0 = by * 256, n0 = bx * 256;
    const int NT = K >> 6, NI = NT >> 1;

    f32x4 acc[8][4];
#pragma unroll
    for (int i = 0; i < 8; i++)
#pragma unroll
        for (int j = 0; j < 4; j++)
#pragma unroll
            for (int r = 0; r < 4; r++) acc[i][j][r] = 0.0f;

    // per-thread staging bases: row rS (0..63), swizzled slot lsS (16B units)
    const int uS = wid * 64 + lane;              // 0..511
    const int rS = uS >> 3;                      // 0..63
    const int lsS = (lane & 7) ^ (rS & 7);
    const u16* pA = A + (size_t)(m0 + rS) * lda + lsS * 8;
    const u16* pB = B + (size_t)(n0 + rS) * ldb + lsS * 8;
    // stage half h (128 rows) of tile t. LDS[r][s] = G[r][s ^ (r&7)].
    auto stgA = [&](int t, int h) {
        u16* dst = &lA[t & 1][h * 8192 + uS * 8];
        const u16* src = pA + (size_t)h * 128 * lda + (t << 6);
        gld16(src, dst);
        gld16(src + (size_t)64 * lda, dst + 4096);
    };
    auto stgB = [&](int t, int h) {
        u16* dst = &lB[t & 1][h * 8192 + uS * 8];
        const u16* src = pB + (size_t)h * 128 * ldb + (t << 6);
        gld16(src, dst);
        gld16(src + (size_t)64 * ldb, dst + 4096);
    };
    // readers: de-swizzle ps = ((kh<<2)|sl) ^ (R&7); R&7 == ar&7 here.
    const int psk0 = (sl ^ (ar & 7)) * 8;
    const int psk1 = ((4 | sl) ^ (ar & 7)) * 8;
    const int aoff = wr * 8192 + ar * 64;                       // A rows wr*128+..
    const int boff = (wc >> 1) * 8192 + (wc & 1) * 4096 + ar * 64;
    auto rdA = [&](int buf, int mi, int kh) -> bf16x8 {
        return *(const bf16x8*)&lA[buf][aoff + mi * 1024 + (kh ? psk1 : psk0)];
    };
    auto rdB = [&](int buf, int ni, int kh) -> bf16x8 {
        return *(const bf16x8*)&lB[buf][boff + ni * 1024 + (kh ? psk1 : psk0)];
    };

    // prologue: tile0 fully; tile1's B-H0, B-H1, A-H0 (A-H1 staged at P1).
    stgA(0, 0); stgA(0, 1); stgB(0, 0); stgB(0, 1);
    stgB(1, 0); stgB(1, 1); stgA(1, 0);
    waitv<6>();                      // tile0 landed; 3 halves in flight
    __builtin_amdgcn_s_barrier();

    bf16x8 af[8][2], bf[4][2];
    for (int j = 0; j < NI; ++j) {
        const int a = 2 * j, b = a + 1;
        const bool more = (j + 1 < NI);
        // ---- P1 [buf0]: read af0-3 + bf0-3; stage A-H1(b)
#pragma unroll
        for (int mi = 0; mi < 4; ++mi)
#pragma unroll
            for (int kh = 0; kh < 2; ++kh) af[mi][kh] = rdA(0, mi, kh);
#pragma unroll
        for (int ni = 0; ni < 4; ++ni)
#pragma unroll
            for (int kh = 0; kh < 2; ++kh) bf[ni][kh] = rdB(0, ni, kh);
        stgA(b, 1);
        lgkm0sb();
        __builtin_amdgcn_s_setprio(1);
        MM8(0, 0);
        __builtin_amdgcn_s_setprio(0);
        __builtin_amdgcn_s_barrier();
        // ---- P2: read af4-7; stage B-H0(a+2)
#pragma unroll
        for (int mi = 4; mi < 8; ++mi)
#pragma unroll
            for (int kh = 0; kh < 2; ++kh) af[mi][kh] = rdA(0, mi, kh);
        if (more) stgB(a + 2, 0);
        lgkm0sb();
        __builtin_amdgcn_s_setprio(1);
        MM8(4, 0);
        __builtin_amdgcn_s_setprio(0);
        __builtin_amdgcn_s_barrier();
        // ---- P3: stage B-H1(a+2)
        if (more) stgB(a + 2, 1);
        __builtin_amdgcn_s_setprio(1);
        MM8(0, 2);
        __builtin_amdgcn_s_setprio(0);
        __builtin_amdgcn_s_barrier();
        // ---- P4: stage A-H0(a+2); vmcnt(6) -> buf1 (tile b) resident
        if (more) stgA(a + 2, 0);
        __builtin_amdgcn_s_setprio(1);
        MM8(4, 2);
        __builtin_amdgcn_s_setprio(0);
        if (more) waitv<6>(); else waitv<0>();
        __builtin_amdgcn_s_barrier();
        // ---- P5 [buf1]: read af0-3 + bf0-3; stage A-H1(a+2)
#pragma unroll
        for (int mi = 0; mi < 4; ++mi)
#pragma unroll
            for (int kh = 0; kh < 2; ++kh) af[mi][kh] = rdA(1, mi, kh);
#pragma unroll
        for (int ni = 0; ni < 4; ++ni)
#pragma unroll
            for (int kh = 0; kh < 2; ++kh) bf[ni][kh] = rdB(1, ni, kh);
        if (more) stgA(a + 2, 1);
        lgkm0sb();
        __builtin_amdgcn_s_setprio(1);
        MM8(0, 0);
        __builtin_amdgcn_s_setprio(0);
        __builtin_amdgcn_s_barrier();
        // ---- P6: read af4-7; stage B-H0(b+2)
#pragma unroll
        for (int mi = 4; mi < 8; ++mi)
#pragma unroll
            for (int kh = 0; kh < 2; ++kh) af[mi][kh] = rdA(1, mi, kh);
        if (more) stgB(b + 2, 0);
        lgkm0sb();
        __builtin_amdgcn_s_setprio(1);
        MM8(4, 0);
        __builtin_amdgcn_s_setprio(0);
        __builtin_amdgcn_s_barrier();
        // ---- P7: stage B-H1(b+2)
        if (more) stgB(b + 2, 1);
        __builtin_amdgcn_s_setprio(1);
        MM8(0, 2);
        __builtin_amdgcn_s_setprio(0);
        __builtin_amdgcn_s_barrier();
        // ---- P8: stage A-H0(b+2); vmcnt(6) -> buf0 (tile a+2) resident
        if (more) stgA(b + 2, 0);
        __builtin_amdgcn_s_setprio(1);
        MM8(4, 2);
        __builtin_amdgcn_s_setprio(0);
        if (more) waitv<6>(); else waitv<0>();
        __builtin_amdgcn_s_barrier();
    }

    // ---------------- epilogue ----------------
    if constexpr (EPI == 3) {
        // per-128-col softmax: col group = wave pair wid^1 (same wr), 128 rows/wave
        const float SL = 0.03125f * 1.44269504088896341f;  // 1/sqrt(D)*log2(e)
#pragma unroll
        for (int mi = 0; mi < 8; mi++) {
#pragma unroll
            for (int r = 0; r < 4; r++) {
                float m = acc[mi][0][r];
#pragma unroll
                for (int ni = 1; ni < 4; ni++) m = fmaxf(m, acc[mi][ni][r]);
                m = fmaxf(m, __shfl_xor(m, 1));
                m = fmaxf(m, __shfl_xor(m, 2));
                m = fmaxf(m, __shfl_xor(m, 4));
                m = fmaxf(m, __shfl_xor(m, 8));
                if (ar == 0) sred[0][wid][mi * 16 + sl * 4 + r] = m;
            }
        }
        __syncthreads();
#pragma unroll
        for (int mi = 0; mi < 8; mi++) {
#pragma unroll
            for (int r = 0; r < 4; r++) {
                const int rl = mi * 16 + sl * 4 + r;
                const float mc = fmaxf(sred[0][wid][rl], sred[0][wid ^ 1][rl]);
                float s = 0.0f;
#pragma unroll
                for (int ni = 0; ni < 4; ni++) {
                    float e = exp2f((acc[mi][ni][r] - mc) * SL);
                    acc[mi][ni][r] = e;
                    s += e;
                }
                s += __shfl_xor(s, 1);
                s += __shfl_xor(s, 2);
                s += __shfl_xor(s, 4);
                s += __shfl_xor(s, 8);
                if (ar == 0) sred[1][wid][rl] = s;
            }
        }
        __syncthreads();
        u16* C = (u16*)Cv + (size_t)z * sC;
#pragma unroll
        for (int mi = 0; mi < 8; mi++) {
#pragma unroll
            for (int r = 0; r < 4; r++) {
                const int rl = mi * 16 + sl * 4 + r;
                const float inv = 1.0f / (sred[1][wid][rl] + sred[1][wid ^ 1][rl]);
                const int row = m0 + wr * 128 + rl;
#pragma unroll
                for (int ni = 0; ni < 4; ni++)
                    C[(size_t)row * ldc + n0 + wc * 64 + ni * 16 + ar] =
                        f2bf(acc[mi][ni][r] * inv);
            }
        }
    } else {
        u16* C = (u16*)Cv + (size_t)z * sC;
#pragma unroll
        for (int mi = 0; mi < 8; mi++) {
#pragma unroll
            for (int ni = 0; ni < 4; ni++) {
                const int col = n0 + wc * 64 + ni * 16 + ar;
                const int rowb = m0 + wr * 128 + mi * 16 + sl * 4;
                const float bv = bias[col];
#pragma unroll
                for (int r = 0; r < 4; r++)
                    C[(size_t)(rowb + r) * ldc + col] = f2bf(acc[mi][ni][r] + bv);
            }
        }
    }
}

// ---------------- gemm128: 128x256, 2 phases/K-tile, 3-deep ring -----------
// EPI 1: bf16 out * scale; 2: f32 out + bias
template <int EPI>
__global__ __launch_bounds__(512, 1) void gemm128(
    const u16* __restrict__ A, const u16* __restrict__ B, void* __restrict__ Cv,
    const float* __restrict__ bias, int K, int lda, int ldb, int ldc,
    long sA, long sB, long sC, float scale)
{
    __shared__ u16 lA[3][128 * 64];
    __shared__ u16 lB[3][256 * 64];
    const int tid = threadIdx.x, lane = tid & 63, wid = tid >> 6;
    const int wr = wid >> 2, wc = wid & 3;
    const int ar = lane & 15, sl = lane >> 4;
    const int z = blockIdx.z;
    A += (size_t)z * sA;
    B += (size_t)z * sB;
    int bx, by;
    xcd_map(bx, by);
    const int m0 = by * 128, n0 = bx * 256;
    const int NT = K >> 6;

    f32x4 acc[4][4];
#pragma unroll
    for (int i = 0; i < 4; i++)
#pragma unroll
        for (int j = 0; j < 4; j++)
#pragma unroll
            for (int r = 0; r < 4; r++) acc[i][j][r] = 0.0f;

    auto stgA = [&](int t) {
        u16* dst = &lA[t % 3][0];
#pragma unroll
        for (int j = 0; j < 2; ++j) {
            const int u = j * 512 + wid * 64 + lane;
            const int row = u >> 3;
            const int ls = (u & 7) ^ (row & 7);
            gld16(A + (size_t)(m0 + row) * lda + (t << 6) + ls * 8, dst + u * 8);
        }
    };
    auto stgB = [&](int t, int h) {
        u16* dst = &lB[t % 3][0];
#pragma unroll
        for (int j = 0; j < 2; ++j) {
            const int u = j * 512 + wid * 64 + lane;
            const int row = h * 128 + (u >> 3);
            const int ls = (u & 7) ^ (row & 7);
            gld16(B + (size_t)(n0 + row) * ldb + (t << 6) + ls * 8, dst + h * 8192 + u * 8);
        }
    };
    auto rd = [&](const u16* l, int R, int kh) -> bf16x8 {
        const int ps = ((kh << 2) | sl) ^ (R & 7);
        return *(const bf16x8*)&l[R * 64 + ps * 8];
    };

    stgA(0); stgB(0, 0); stgB(0, 1);
    stgA(1); stgB(1, 0); stgB(1, 1);
    waitv<6>();
    __builtin_amdgcn_s_barrier();

    bf16x8 af[4][2], bf[2][2];
    for (int t = 0; t < NT; ++t) {
        const u16* bufA = &lA[t % 3][0];
        const u16* bufB = &lB[t % 3][0];
        const bool s2 = (t + 2 < NT);
#pragma unroll
        for (int mi = 0; mi < 4; ++mi)
#pragma unroll
            for (int kh = 0; kh < 2; ++kh)
                af[mi][kh] = rd(bufA, wr * 64 + mi * 16 + ar, kh);
#pragma unroll
        for (int ni = 0; ni < 2; ++ni)
#pragma unroll
            for (int kh = 0; kh < 2; ++kh)
                bf[ni][kh] = rd(bufB, wc * 64 + ni * 16 + ar, kh);
        if (s2) { stgA(t + 2); stgB(t + 2, 0); }
        lgkm0sb();
        __builtin_amdgcn_s_setprio(1);
#pragma unroll
        for (int mi = 0; mi < 4; ++mi)
#pragma unroll
            for (int ni = 0; ni < 2; ++ni)
#pragma unroll
                for (int kh = 0; kh < 2; ++kh)
                    acc[mi][ni] = __builtin_amdgcn_mfma_f32_16x16x32_bf16(
                        af[mi][kh], bf[ni][kh], acc[mi][ni], 0, 0, 0);
        __builtin_amdgcn_s_setprio(0);
        __builtin_amdgcn_s_barrier();
#pragma unroll
        for (int ni = 0; ni < 2; ++ni)
#pragma unroll
            for (int kh = 0; kh < 2; ++kh)
                bf[ni][kh] = rd(bufB, wc * 64 + (2 + ni) * 16 + ar, kh);
        if (s2) stgB(t + 2, 1);
        lgkm0sb();
        __builtin_amdgcn_s_setprio(1);
#pragma unroll
        for (int mi = 0; mi < 4; ++mi)
#pragma unroll
            for (int ni = 0; ni < 2; ++ni)
#pragma unroll
                for (int kh = 0; kh < 2; ++kh)
                    acc[mi][2 + ni] = __builtin_amdgcn_mfma_f32_16x16x32_bf16(
                        af[mi][kh], bf[ni][kh], acc[mi][2 + ni], 0, 0, 0);
        __builtin_amdgcn_s_setprio(0);
        if (s2) waitv<6>(); else waitv<0>();
        __builtin_amdgcn_s_barrier();
    }

#pragma unroll
    for (int mi = 0; mi < 4; mi++) {
#pragma unroll
        for (int ni = 0; ni < 4; ni++) {
            const int col = n0 + wc * 64 + ni * 16 + ar;
            const int rowb = m0 + wr * 64 + mi * 16 + sl * 4;
            if constexpr (EPI == 1) {
                u16* C = (u16*)Cv + (size_t)z * sC;
#pragma unroll
                for (int r = 0; r < 4; r++)
                    C[(size_t)(rowb + r) * ldc + col] = f2bf(acc[mi][ni][r] * scale);
            } else {
                float* C = (float*)Cv + (size_t)z * sC;
                const float bv = bias[col];
#pragma unroll
                for (int r = 0; r < 4; r++)
                    C[(size_t)(rowb + r) * ldc + col] = acc[mi][ni][r] + bv;
            }
        }
    }
}

// ---------------- launch ----------------
extern "C" void kernel_launch(void* const* d_in, const int* in_sizes, int n_in,
                              void* d_out, int out_size, void* d_ws, size_t ws_size,
                              hipStream_t stream)
{
    const float* X  = (const float*)d_in[0];
    const float* Wq = (const float*)d_in[1];
    const float* bq = (const float*)d_in[2];
    const float* Wk = (const float*)d_in[3];
    const float* bk = (const float*)d_in[4];
    const float* Wv = (const float*)d_in[5];
    const float* bv = (const float*)d_in[6];
    const float* Wo = (const float*)d_in[7];
    const float* bo = (const float*)d_in[8];
    float* OUT = (float*)d_out;

    u16* ws = (u16*)d_ws;
    const size_t NTOK = (size_t)B_ * S_;         // 8192
    const size_t XSZ = NTOK * D_;                // 8.39M elems
    u16* Xb   = ws;                              // [8192,1024] (reused as Ob)
    u16* QKVb = Xb + XSZ;                        // [8192,3072]
    u16* Vt   = QKVb + NTOK * (size_t)(3 * D_);  // [B][1024][4096]
    u16* Wqb  = Vt + XSZ;                        // [Wq;Wk;Wv;Wo] contiguous
    u16* Wsm  = Wqb + (size_t)4 * D_ * D_;       // [B][4096][4096]
    float* bqkv = (float*)(Wsm + (size_t)B_ * S_ * S_);  // [3072] f32
    u16* Ob   = Xb;

    u16* Qp = QKVb;
    u16* Kp = QKVb + D_;
    u16* Vp = QKVb + 2 * D_;
    const int ldqkv = 3 * D_;

    cast_kernel<<<dim3(2048), dim3(256), 0, stream>>>(X, Xb, (int)(XSZ / 8));
    cast4_kernel<<<dim3(512, 4), dim3(256), 0, stream>>>(Wq, Wk, Wv, Wo, Wqb,
                                                         (int)((size_t)D_ * D_ / 8));
    concat_bias<<<dim3(12), dim3(256), 0, stream>>>(bq, bk, bv, bqkv);

    // Fused QKV projection: [8192,1024] x [3072,1024]^T -> [8192,3072]
    gemm256<0><<<dim3(3 * D_ / 256, NTOK / 256, 1), 512, 0, stream>>>(
        Xb, Wqb, QKVb, bqkv, D_, D_, D_, ldqkv, 0, 0, 0);

    transpose_v<<<dim3(D_ / 64, S_ / 64, B_), 256, 0, stream>>>(Vp, Vt, ldqkv);

    // Scores + fused per-tile softmax: [4096,1024] x [4096,1024]^T
    gemm256<3><<<dim3(S_ / 256, S_ / 256, B_), 512, 0, stream>>>(
        Qp, Kp, Wsm, nullptr, D_, ldqkv, ldqkv, S_,
        (long)S_ * ldqkv, (long)S_ * ldqkv, (long)S_ * S_);

    // PV: [4096,4096] x [1024,4096]^T -> [4096,1024], scaled by 1/T
    gemm128<1><<<dim3(D_ / 256, S_ / 128, B_), 512, 0, stream>>>(
        Wsm, Vt, Ob, nullptr, S_, S_, S_, D_,
        (long)S_ * S_, (long)D_ * S_, (long)S_ * D_, 1.0f / (32.0f + 1e-6f));

    // Output projection: [8192,1024] x [1024,1024]^T -> f32 OUT
    gemm128<2><<<dim3(D_ / 256, NTOK / 128, 1), 512, 0, stream>>>(
        Ob, Wqb + (size_t)3 * D_ * D_, OUT, bo, D_, D_, D_, D_, 0, 0, 0, 1.0f);
}